// Round 2
// baseline (665.732 us; speedup 1.0000x reference)
//
#include <hip/hip_runtime.h>
#include <hip/hip_bf16.h>

#define N_NODES  50000
#define N_EDGES  800000
#define NDIM_IN  64
#define EDIMS    64
#define NDIM_OUT 128

typedef __bf16 bf16;
typedef bf16  bf16x8 __attribute__((ext_vector_type(8)));
typedef float f32x4  __attribute__((ext_vector_type(4)));

// ---------------------------------------------------------------------------
// Runtime dtype detection (harness dtype is ambiguous; round-1 inf implies
// fp32 floats, but we guard both ways so either interpretation is correct).
// ---------------------------------------------------------------------------
__device__ __forceinline__ bool detect_f32(const void* nfeats) {
    // bf16 N(0,1) samples: exponent field in [100,134]. fp32 low-mantissa
    // halves (even uint16 words, little-endian): ~uniform random.
    const unsigned short* w = (const unsigned short*)nfeats;
    for (int i = 0; i < 64; i += 2) {
        const int e = (w[i] >> 7) & 0xFF;
        if (e < 100 || e > 134) return true;
    }
    return false;
}
__device__ __forceinline__ bool detect_i64(const int* p) {
    // int64 indices < 2^31: every odd int32 word is zero.
    for (int i = 1; i < 64; i += 2) if (p[i] != 0) return false;
    return true;
}

// load 8 consecutive elements as bf16x8 from either fp32 or bf16 storage
__device__ __forceinline__ bf16x8 load8(const void* p, int off, bool f32) {
    if (f32) {
        const float* q = (const float*)p + off;
        const f32x4 a = *(const f32x4*)q;
        const f32x4 b = *(const f32x4*)(q + 4);
        bf16x8 r;
        #pragma unroll
        for (int u = 0; u < 4; ++u) { r[u] = (bf16)a[u]; r[4 + u] = (bf16)b[u]; }
        return r;
    }
    return *(const bf16x8*)((const bf16*)p + off);
}
__device__ __forceinline__ float loadf(const void* p, int i, bool f32) {
    return f32 ? ((const float*)p)[i] : (float)((const bf16*)p)[i];
}
__device__ __forceinline__ void storef(void* p, int i, float v, bool f32) {
    if (f32) ((float*)p)[i] = v; else ((bf16*)p)[i] = (bf16)v;
}

// ---------------------------------------------------------------------------
// Kernel A: per-edge message = relu([nfeats[src], efeats] @ W_msg + b_msg),
// scatter-added into fp32 h_neigh[dst] via HW fp32 atomics.
// One wave = 16 edges; A-frags (A[m=lane&15][k=quad*8+j]) direct from global;
// W_msg^T staged once per block in LDS (stride 136 bf16: 16B-aligned, 2-way
// bank aliasing = free on gfx950).
// ---------------------------------------------------------------------------
__global__ __launch_bounds__(256) void edge_msg_kernel(
    const void* __restrict__ nfeats,
    const void* __restrict__ efeats,
    const void* __restrict__ W_msg,
    const void* __restrict__ b_msg,
    const int*  __restrict__ src,
    const int*  __restrict__ dst,
    float*      __restrict__ h_neigh)
{
    __shared__ bf16 sWT[128 * 136];
    __shared__ int s_flags;

    const int tid = threadIdx.x;
    if (tid == 0)
        s_flags = (detect_f32(nfeats) ? 1 : 0) | (detect_i64(dst) ? 2 : 0);
    __syncthreads();
    const bool f32 = (s_flags & 1) != 0;
    const int  ish = (s_flags & 2) ? 1 : 0;   // int64 -> read low word at 2*i

    // stage W_msg^T: 128x128, 2048 8-elem chunks, 8 iters x 256 threads
    #pragma unroll
    for (int it = 0; it < 8; ++it) {
        const int task = it * 256 + tid;
        const int k = task >> 4;      // 0..127 (input dim)
        const int c = task & 15;      // chunk of 8 consecutive n
        const bf16x8 w = load8(W_msg, k * 128 + c * 8, f32);
        #pragma unroll
        for (int u = 0; u < 8; ++u) sWT[(c * 8 + u) * 136 + k] = w[u];
    }
    __syncthreads();

    const int wave = tid >> 6;
    const int lane = tid & 63;
    const int m    = lane & 15;   // A row / B col / C col
    const int quad = lane >> 4;   // k-group / C row group

    const int nchunks = N_EDGES / 64;   // 12500, exact
    for (int chunk = blockIdx.x; chunk < nchunks; chunk += gridDim.x) {
        const int ebase = chunk * 64 + wave * 16;
        const int e_m   = ebase + m;            // edge owning this lane's A row
        const int s     = src[e_m << ish];

        bf16x8 a[4];
        a[0] = load8(nfeats, s   * 64 +      quad * 8, f32);   // k 0..31
        a[1] = load8(nfeats, s   * 64 + 32 + quad * 8, f32);   // k 32..63
        a[2] = load8(efeats, e_m * 64 +      quad * 8, f32);   // k 64..95
        a[3] = load8(efeats, e_m * 64 + 32 + quad * 8, f32);   // k 96..127

        int drow[4];
        #pragma unroll
        for (int i = 0; i < 4; ++i)
            drow[i] = dst[(ebase + quad * 4 + i) << ish] * 128;  // C row = quad*4+i

        #pragma unroll
        for (int t = 0; t < 8; ++t) {   // 8 n-tiles of 16 output cols
            f32x4 acc = {0.f, 0.f, 0.f, 0.f};
            const bf16* bp = sWT + (t * 16 + m) * 136 + quad * 8;
            #pragma unroll
            for (int kb = 0; kb < 4; ++kb)
                acc = __builtin_amdgcn_mfma_f32_16x16x32_bf16(
                          a[kb], *(const bf16x8*)(bp + kb * 32), acc, 0, 0, 0);
            const int   n    = t * 16 + m;
            const float bias = loadf(b_msg, n, f32);
            #pragma unroll
            for (int i = 0; i < 4; ++i) {
                float v = acc[i] + bias;
                v = v > 0.f ? v : 0.f;
                unsafeAtomicAdd(h_neigh + drow[i] + n, v);
            }
        }
    }
}

// ---------------------------------------------------------------------------
// Kernel B: out = relu([nfeats, h_neigh] @ W_apply + b_apply), K=192.
// h_neigh is our fp32 scratch; everything else dual-dtype.
// ---------------------------------------------------------------------------
__global__ __launch_bounds__(256) void apply_kernel(
    const void*  __restrict__ nfeats,
    const float* __restrict__ h_neigh,
    const void*  __restrict__ W_apply,
    const void*  __restrict__ b_apply,
    void*        __restrict__ out)
{
    __shared__ bf16 sWT[128 * 200];   // [n][k], k<192, stride 200 (16B-aligned)
    __shared__ int s_flags;

    const int tid = threadIdx.x;
    if (tid == 0) s_flags = detect_f32(nfeats) ? 1 : 0;
    __syncthreads();
    const bool f32 = (s_flags & 1) != 0;

    // stage W_apply^T: 192x128, 3072 8-elem chunks, 12 iters x 256 threads
    #pragma unroll
    for (int it = 0; it < 12; ++it) {
        const int task = it * 256 + tid;
        const int k = task >> 4;      // 0..191
        const int c = task & 15;
        const bf16x8 w = load8(W_apply, k * 128 + c * 8, f32);
        #pragma unroll
        for (int u = 0; u < 8; ++u) sWT[(c * 8 + u) * 200 + k] = w[u];
    }
    __syncthreads();

    const int wave = tid >> 6;
    const int lane = tid & 63;
    const int m    = lane & 15;
    const int quad = lane >> 4;

    const int nchunks = (N_NODES + 63) / 64;   // 782
    for (int chunk = blockIdx.x; chunk < nchunks; chunk += gridDim.x) {
        const int nbase = chunk * 64 + wave * 16;
        const int nm  = nbase + m;
        const int nmc = nm < N_NODES ? nm : N_NODES - 1;   // clamp tail reads

        bf16x8 a[6];
        a[0] = load8(nfeats, nmc * 64 +      quad * 8, f32);   // k 0..31
        a[1] = load8(nfeats, nmc * 64 + 32 + quad * 8, f32);   // k 32..63
        #pragma unroll
        for (int kb = 0; kb < 4; ++kb) {                       // k 64..191
            const float* hp = h_neigh + nmc * 128 + kb * 32 + quad * 8;
            const f32x4 p = *(const f32x4*)(hp);
            const f32x4 q = *(const f32x4*)(hp + 4);
            bf16x8 r;
            #pragma unroll
            for (int u = 0; u < 4; ++u) { r[u] = (bf16)p[u]; r[4 + u] = (bf16)q[u]; }
            a[2 + kb] = r;
        }

        #pragma unroll
        for (int t = 0; t < 8; ++t) {
            f32x4 acc = {0.f, 0.f, 0.f, 0.f};
            const bf16* bp = sWT + (t * 16 + m) * 200 + quad * 8;
            #pragma unroll
            for (int kb = 0; kb < 6; ++kb)
                acc = __builtin_amdgcn_mfma_f32_16x16x32_bf16(
                          a[kb], *(const bf16x8*)(bp + kb * 32), acc, 0, 0, 0);
            const int   n    = t * 16 + m;
            const float bias = loadf(b_apply, n, f32);
            #pragma unroll
            for (int i = 0; i < 4; ++i) {
                const int row = nbase + quad * 4 + i;
                if (row < N_NODES) {
                    float v = acc[i] + bias;
                    v = v > 0.f ? v : 0.f;
                    storef(out, row * 128 + n, v, f32);
                }
            }
        }
    }
}

extern "C" void kernel_launch(void* const* d_in, const int* in_sizes, int n_in,
                              void* d_out, int out_size, void* d_ws, size_t ws_size,
                              hipStream_t stream) {
    const void* nfeats  = d_in[0];
    const void* efeats  = d_in[1];
    const void* W_msg   = d_in[2];
    const void* b_msg   = d_in[3];
    const void* W_apply = d_in[4];
    const void* b_apply = d_in[5];
    const int*  src     = (const int*)d_in[6];
    const int*  dst     = (const int*)d_in[7];
    float*      h_neigh = (float*)d_ws;        // 50000*128 fp32 = 25.6 MB

    // zero the fp32 aggregation buffer (ws is re-poisoned to 0xAA every call)
    hipMemsetAsync(h_neigh, 0, (size_t)N_NODES * NDIM_OUT * sizeof(float), stream);

    edge_msg_kernel<<<768, 256, 0, stream>>>(nfeats, efeats, W_msg, b_msg, src, dst, h_neigh);
    apply_kernel<<<512, 256, 0, stream>>>(nfeats, h_neigh, W_apply, b_apply, d_out);
}